// Round 7
// baseline (236.053 us; speedup 1.0000x reference)
//
#include <hip/hip_runtime.h>
#include <hip/hip_bf16.h>
#include <stdint.h>

#define Bn 4
#define Cn 64
#define Fn 50000
#define Kn 16
#define NTOT (Bn*Fn)
#define EPS 1e-5f

typedef unsigned short u16;
typedef unsigned int u32;
typedef __attribute__((ext_vector_type(8))) short short8;
typedef __attribute__((ext_vector_type(4))) float f32x4;

__device__ __forceinline__ u16 f2bf(float x) {
  __hip_bfloat16 h = __float2bfloat16(x);
  return *reinterpret_cast<u16*>(&h);
}
__device__ __forceinline__ u32 pack2(float a, float b) {
  return (u32)f2bf(a) | ((u32)f2bf(b) << 16);
}

// K1 (MFMA, LDS-free): Gt[(b*4+seg)][f][16ch] bf16 (32 B rows) = W x fea[b].
// Block: 64o x 256f, one wave owns 64 f. B-frags loaded straight from global
// in MFMA layout (lane=face, 8 consecutive-c scalars). Layouts (m89-verified):
//   A[m=lane&15][k=quad*8+j], B[k=quad*8+j][n=lane&15], D: row=quad*4+r, col=lane&15.
__global__ __launch_bounds__(256) void k1_mfma(
    const float* __restrict__ fea, const float* __restrict__ W,
    u32* __restrict__ Gt) {
  const int b = blockIdx.y;
  const int f0 = blockIdx.x * 256;
  const int t = threadIdx.x;
  const int l = t & 63;
  const int quad = l >> 4;
  const int lane15 = l & 15;
  const int wv = t >> 6;

  // A-frags: o = ot*16 + lane15, c = kk*32 + quad*8 + j
  short8 afr[4][2];
  #pragma unroll
  for (int ot = 0; ot < 4; ot++) {
    #pragma unroll
    for (int kk = 0; kk < 2; kk++) {
      const float* wr = W + (ot * 16 + lane15) * 64 + kk * 32 + quad * 8;
      float4 wa = *(const float4*)wr;
      float4 wb = *(const float4*)(wr + 4);
      union { short8 v; u32 u[4]; } fr;
      fr.u[0] = pack2(wa.x, wa.y); fr.u[1] = pack2(wa.z, wa.w);
      fr.u[2] = pack2(wb.x, wb.y); fr.u[3] = pack2(wb.z, wb.w);
      afr[ot][kk] = fr.v;
    }
  }

  const float* fb = fea + (size_t)b * Cn * Fn;
  f32x4 acc[4][4];
  #pragma unroll
  for (int ot = 0; ot < 4; ot++)
    #pragma unroll
    for (int ft = 0; ft < 4; ft++) acc[ot][ft] = (f32x4){0.f, 0.f, 0.f, 0.f};

  #pragma unroll
  for (int ft = 0; ft < 4; ft++) {
    const int fg = f0 + wv * 64 + ft * 16 + lane15;
    const bool v = fg < Fn;
    float x[16];
    #pragma unroll
    for (int j = 0; j < 8; j++)
      x[j] = v ? fb[(size_t)(quad * 8 + j) * Fn + fg] : 0.f;
    #pragma unroll
    for (int j = 0; j < 8; j++)
      x[8 + j] = v ? fb[(size_t)(32 + quad * 8 + j) * Fn + fg] : 0.f;
    union { short8 s; u32 u[4]; } b0, b1;
    #pragma unroll
    for (int p = 0; p < 4; p++) {
      b0.u[p] = pack2(x[2 * p], x[2 * p + 1]);
      b1.u[p] = pack2(x[8 + 2 * p], x[8 + 2 * p + 1]);
    }
    #pragma unroll
    for (int ot = 0; ot < 4; ot++) {
      acc[ot][ft] = __builtin_amdgcn_mfma_f32_16x16x32_bf16(afr[ot][0], b0.s, acc[ot][ft], 0, 0, 0);
      acc[ot][ft] = __builtin_amdgcn_mfma_f32_16x16x32_bf16(afr[ot][1], b1.s, acc[ot][ft], 0, 0, 0);
    }
  }

  // Epilogue: o = ot*16 + quad*4 + r -> seg = ot, uint2 at u32-offset quad*2
  #pragma unroll
  for (int ot = 0; ot < 4; ot++) {
    #pragma unroll
    for (int ft = 0; ft < 4; ft++) {
      int fg = f0 + wv * 64 + ft * 16 + lane15;
      if (fg < Fn) {
        uint2 pv;
        pv.x = pack2(acc[ot][ft][0], acc[ot][ft][1]);
        pv.y = pack2(acc[ot][ft][2], acc[ot][ft][3]);
        *(uint2*)(Gt + ((size_t)(b * 4 + ot) * Fn + fg) * 8 + quad * 2) = pv;
      }
    }
  }
}

// K2: unchanged from R3/R5 (best measured: 68 us). block = (b,seg) x 128 faces,
// 32 B rows, 2 lanes/row.
template<int WRITE_BF16>
__global__ __launch_bounds__(256) void k2_gather(
    const u32* __restrict__ Gt, const int* __restrict__ ring,
    const float* __restrict__ bias, u32* __restrict__ Y, float* __restrict__ outF,
    float* __restrict__ gsum, float* __restrict__ gsum2) {
  const int bid = blockIdx.x;
  const int combo = bid & 15;
  const int ft = bid >> 4;
  const int b = combo >> 2;
  const int seg = combo & 3;
  const int t = threadIdx.x;
  const int face_l = t >> 1;          // 0..127
  const int half = t & 1;
  const int fa = ft * 128 + face_l;
  const bool valid = fa < Fn;

  __shared__ float y_s[128][17];
  __shared__ float rs[16][17];
  __shared__ float rs2[16][17];

  float acc[8];
  #pragma unroll
  for (int i = 0; i < 8; i++) acc[i] = 0.f;

  const int c0 = seg * 16 + half * 8;
  float bv[8];
  #pragma unroll
  for (int i = 0; i < 8; i++) bv[i] = bias[c0 + i];

  if (valid) {
    const int4* rp = (const int4*)(ring + ((size_t)b * Fn + fa) * Kn);
    int4 i0 = rp[0], i1 = rp[1], i2 = rp[2], i3 = rp[3];
    int idx[16] = {i0.x,i0.y,i0.z,i0.w, i1.x,i1.y,i1.z,i1.w,
                   i2.x,i2.y,i2.z,i2.w, i3.x,i3.y,i3.z,i3.w};
    const uint4* Gs = (const uint4*)(Gt + (size_t)combo * Fn * 8);
    uint4 v[8], w[8];
    #pragma unroll
    for (int k = 0; k < 8; k++) v[k] = Gs[(size_t)idx[k] * 2 + half];
    #pragma unroll
    for (int k = 0; k < 8; k++) w[k] = Gs[(size_t)idx[8 + k] * 2 + half];
    #pragma unroll
    for (int k = 0; k < 8; k++) {
      u32 uu[4] = {v[k].x, v[k].y, v[k].z, v[k].w};
      #pragma unroll
      for (int p = 0; p < 4; p++) {
        acc[2*p]   += __uint_as_float(uu[p] << 16);
        acc[2*p+1] += __uint_as_float(uu[p] & 0xffff0000u);
      }
    }
    #pragma unroll
    for (int k = 0; k < 8; k++) {
      u32 uu[4] = {w[k].x, w[k].y, w[k].z, w[k].w};
      #pragma unroll
      for (int p = 0; p < 4; p++) {
        acc[2*p]   += __uint_as_float(uu[p] << 16);
        acc[2*p+1] += __uint_as_float(uu[p] & 0xffff0000u);
      }
    }
  }
  #pragma unroll
  for (int i = 0; i < 8; i++) acc[i] = valid ? acc[i] + bv[i] : 0.f;
  #pragma unroll
  for (int i = 0; i < 8; i++) y_s[face_l][half * 8 + i] = acc[i];
  __syncthreads();

  if (WRITE_BF16) {
    const int fp = t & 63, chb = t >> 6;   // 64 face-pairs x 4 ch-groups
    const int fa2 = ft * 64 + fp;
    if (fa2 * 2 < Fn) {
      #pragma unroll
      for (int j = 0; j < 4; j++) {
        int ch = chb * 4 + j;
        Y[((size_t)b * 64 + seg * 16 + ch) * (Fn / 2) + fa2] =
            pack2(y_s[fp * 2][ch], y_s[fp * 2 + 1][ch]);
      }
    }
  } else {
    const int fl2 = t & 127, chb = t >> 7;
    if (ft * 128 + fl2 < Fn) {
      float* ob = outF + ((size_t)b * 64 + seg * 16 + chb * 8) * Fn + ft * 128 + fl2;
      #pragma unroll
      for (int j = 0; j < 8; j++) ob[(size_t)j * Fn] = y_s[fl2][chb * 8 + j];
    }
  }

  {  // stats: 16 parts x 16 channels
    const int ch = t & 15, part = t >> 4;
    float s = 0.f, s2 = 0.f;
    #pragma unroll
    for (int i = 0; i < 8; i++) {
      float v = y_s[part * 8 + i][ch];
      s += v; s2 += v * v;
    }
    rs[part][ch] = s; rs2[part][ch] = s2;
  }
  __syncthreads();
  if (t < 16) {
    float s = 0.f;
    #pragma unroll
    for (int p = 0; p < 16; p++) s += rs[p][t];
    atomicAdd(&gsum[seg * 16 + t], s);
  } else if (t < 32) {
    const int ch = t - 16;
    float s2 = 0.f;
    #pragma unroll
    for (int p = 0; p < 16; p++) s2 += rs2[p][ch];
    atomicAdd(&gsum2[seg * 16 + ch], s2);
  }
}

__global__ void k3_stats(const float* __restrict__ gsum, const float* __restrict__ gsum2,
                         const float* __restrict__ gamma, const float* __restrict__ beta,
                         float* __restrict__ ab) {
  int o = threadIdx.x;
  if (o < 64) {
    float inv = 1.0f / (float)NTOT;
    float mean = gsum[o] * inv;
    float var = gsum2[o] * inv - mean * mean;  // biased
    float r = rsqrtf(var + EPS);
    float a = gamma[o] * r;
    ab[o] = a;
    ab[64 + o] = beta[o] - mean * a;
  }
}

// k4 (bf16, k3 fused): derives (a,c) per channel from gsum/gsum2 (L2-hot),
// reads uint4 (8 faces), writes two float4. R6 bug fixed: proper r[8] array
// (no OOB write through &o0.x).
__global__ __launch_bounds__(256) void k4_norm_bf(
    const u32* __restrict__ Y, const float* __restrict__ gsum,
    const float* __restrict__ gsum2, const float* __restrict__ gamma,
    const float* __restrict__ beta, float* __restrict__ out) {
  int i = blockIdx.x * 256 + threadIdx.x;   // uint4 index; 1.6M total, exact cover
  int ch = (i / 6250) & 63;                 // Fn/8 = 6250 uint4 per channel row
  const float inv = 1.0f / (float)NTOT;
  float mean = gsum[ch] * inv;
  float var = gsum2[ch] * inv - mean * mean;
  float a = gamma[ch] * rsqrtf(var + EPS);
  float cc = beta[ch] - mean * a;
  uint4 u = ((const uint4*)Y)[i];
  u32 uu[4] = {u.x, u.y, u.z, u.w};
  float r[8];
  #pragma unroll
  for (int p = 0; p < 4; p++) {
    r[2*p]   = fmaxf(fmaf(__uint_as_float(uu[p] << 16), a, cc), 0.f);
    r[2*p+1] = fmaxf(fmaf(__uint_as_float(uu[p] & 0xffff0000u), a, cc), 0.f);
  }
  float4 o0 = make_float4(r[0], r[1], r[2], r[3]);
  float4 o1 = make_float4(r[4], r[5], r[6], r[7]);
  ((float4*)out)[i * 2] = o0;
  ((float4*)out)[i * 2 + 1] = o1;
}

// k4 (fallback): in-place fp32 normalize
__global__ __launch_bounds__(256) void k4_norm_f32(float* __restrict__ out,
                                                   const float* __restrict__ ab) {
  int i = blockIdx.x * 256 + threadIdx.x;   // float4 index
  int o = (i / (Fn / 4)) & 63;
  float a = ab[o], c = ab[64 + o];
  float4 v = ((float4*)out)[i];
  v.x = fmaxf(fmaf(v.x, a, c), 0.f);
  v.y = fmaxf(fmaf(v.y, a, c), 0.f);
  v.z = fmaxf(fmaf(v.z, a, c), 0.f);
  v.w = fmaxf(fmaf(v.w, a, c), 0.f);
  ((float4*)out)[i] = v;
}

extern "C" void kernel_launch(void* const* d_in, const int* in_sizes, int n_in,
                              void* d_out, int out_size, void* d_ws, size_t ws_size,
                              hipStream_t stream) {
  const float* fea   = (const float*)d_in[0];
  const int*   ring  = (const int*)d_in[1];
  const float* W     = (const float*)d_in[2];
  const float* bias  = (const float*)d_in[3];
  const float* gamma = (const float*)d_in[4];
  const float* beta  = (const float*)d_in[5];
  float* out = (float*)d_out;

  u32* Gt = (u32*)d_ws;                                   // [B*4][Fn][8 u32] = 25.6 MB
  const size_t gtBytes = (size_t)Bn * 4 * Fn * 8 * 4;
  const size_t yBytes  = (size_t)Bn * 64 * (Fn / 2) * 4;  // 25.6 MB
  const bool bf16y = ws_size >= gtBytes + yBytes + 1024;

  u32* Y = (u32*)((char*)d_ws + gtBytes);
  float* gsum  = bf16y ? (float*)((char*)d_ws + gtBytes + yBytes)
                       : (float*)((char*)d_ws + gtBytes);
  float* gsum2 = gsum + 64;
  float* ab    = gsum + 128;

  hipMemsetAsync(gsum, 0, 2 * 64 * sizeof(float), stream);
  k1_mfma<<<dim3((Fn + 255) / 256, Bn), 256, 0, stream>>>(fea, W, Gt);
  const int ftiles = (Fn + 127) / 128;                    // 391
  if (bf16y) {
    k2_gather<1><<<dim3(ftiles * 16), 256, 0, stream>>>(Gt, ring, bias, Y, out, gsum, gsum2);
    k4_norm_bf<<<dim3(Bn * 64 * 6250 / 256), 256, 0, stream>>>(Y, gsum, gsum2, gamma, beta, out);
  } else {
    k2_gather<0><<<dim3(ftiles * 16), 256, 0, stream>>>(Gt, ring, bias, Y, out, gsum, gsum2);
    k3_stats<<<1, 64, 0, stream>>>(gsum, gsum2, gamma, beta, ab);
    k4_norm_f32<<<dim3((Bn * Cn * Fn / 4) / 256), 256, 0, stream>>>(out, ab);
  }
}

// Round 8
// 197.395 us; speedup vs baseline: 1.1958x; 1.1958x over previous
//
#include <hip/hip_runtime.h>
#include <hip/hip_bf16.h>
#include <stdint.h>

#define Bn 4
#define Cn 64
#define Fn 50000
#define Kn 16
#define NTOT (Bn*Fn)
#define EPS 1e-5f

typedef unsigned short u16;
typedef unsigned int u32;
typedef __attribute__((ext_vector_type(8))) short short8;
typedef __attribute__((ext_vector_type(4))) float f32x4;

__device__ __forceinline__ u16 f2bf(float x) {
  __hip_bfloat16 h = __float2bfloat16(x);
  return *reinterpret_cast<u16*>(&h);
}
__device__ __forceinline__ u32 pack2(float a, float b) {
  return (u32)f2bf(a) | ((u32)f2bf(b) << 16);
}

// K1 (MFMA): Gt[(b*4+seg)][f][16ch] bf16 (32 B rows) = W x fea[b].
// 128-f tile. fea staged via wide coalesced float4 loads into LDS [c][f] fp32
// (row stride 129 dwords -> frag reads are <=2-way bank aliased = free);
// B-frags built from 16 ds_read_b32. MFMA layouts (m89-verified):
//   A[m=lane&15][k=quad*8+j], B[k=quad*8+j][n=lane&15], D: row=quad*4+r, col=lane&15.
__global__ __launch_bounds__(256) void k1_mfma(
    const float* __restrict__ fea, const float* __restrict__ W,
    u32* __restrict__ Gt) {
  const int b = blockIdx.y;
  const int f0 = blockIdx.x * 128;
  const int t = threadIdx.x;
  const int l = t & 63;
  const int quad = l >> 4;
  const int lane15 = l & 15;
  const int wv = t >> 6;
  __shared__ float a_s[64][129];   // 33 KB -> 4 blocks/CU

  // A-frags: o = ot*16 + lane15, c = kk*32 + quad*8 + j
  short8 afr[4][2];
  #pragma unroll
  for (int ot = 0; ot < 4; ot++) {
    #pragma unroll
    for (int kk = 0; kk < 2; kk++) {
      const float* wr = W + (ot * 16 + lane15) * 64 + kk * 32 + quad * 8;
      float4 wa = *(const float4*)wr;
      float4 wb = *(const float4*)(wr + 4);
      union { short8 v; u32 u[4]; } fr;
      fr.u[0] = pack2(wa.x, wa.y); fr.u[1] = pack2(wa.z, wa.w);
      fr.u[2] = pack2(wb.x, wb.y); fr.u[3] = pack2(wb.z, wb.w);
      afr[ot][kk] = fr.v;
    }
  }

  // Stage: 8 independent float4 loads/thread, each half-wave reads a 512 B run
  {
    const float* fb = fea + (size_t)b * Cn * Fn;
    const int f4 = t & 31;          // float4 slot within 128-f tile
    const int cbase = t >> 5;       // 0..7
    const bool fvalid = (f0 + f4 * 4) < Fn;   // Fn%4==0 -> whole float4 valid
    #pragma unroll
    for (int jj = 0; jj < 8; jj++) {
      int c = cbase + jj * 8;
      float4 v = make_float4(0.f, 0.f, 0.f, 0.f);
      if (fvalid) v = *(const float4*)(fb + (size_t)c * Fn + f0 + f4 * 4);
      *(float4*)&a_s[c][f4 * 4] = v;
    }
  }
  __syncthreads();

  f32x4 acc[4][2];
  #pragma unroll
  for (int ot = 0; ot < 4; ot++)
    #pragma unroll
    for (int ft = 0; ft < 2; ft++) acc[ot][ft] = (f32x4){0.f, 0.f, 0.f, 0.f};

  #pragma unroll
  for (int ft = 0; ft < 2; ft++) {
    const int fl = wv * 32 + ft * 16 + lane15;
    float x[16];
    #pragma unroll
    for (int j = 0; j < 8; j++) x[j] = a_s[quad * 8 + j][fl];
    #pragma unroll
    for (int j = 0; j < 8; j++) x[8 + j] = a_s[32 + quad * 8 + j][fl];
    union { short8 s; u32 u[4]; } b0, b1;
    #pragma unroll
    for (int p = 0; p < 4; p++) {
      b0.u[p] = pack2(x[2 * p], x[2 * p + 1]);
      b1.u[p] = pack2(x[8 + 2 * p], x[8 + 2 * p + 1]);
    }
    #pragma unroll
    for (int ot = 0; ot < 4; ot++) {
      acc[ot][ft] = __builtin_amdgcn_mfma_f32_16x16x32_bf16(afr[ot][0], b0.s, acc[ot][ft], 0, 0, 0);
      acc[ot][ft] = __builtin_amdgcn_mfma_f32_16x16x32_bf16(afr[ot][1], b1.s, acc[ot][ft], 0, 0, 0);
    }
  }

  // Epilogue: o = ot*16 + quad*4 + r -> seg = ot, uint2 at u32-offset quad*2
  #pragma unroll
  for (int ot = 0; ot < 4; ot++) {
    #pragma unroll
    for (int ft = 0; ft < 2; ft++) {
      int fg = f0 + wv * 32 + ft * 16 + lane15;
      if (fg < Fn) {
        uint2 pv;
        pv.x = pack2(acc[ot][ft][0], acc[ot][ft][1]);
        pv.y = pack2(acc[ot][ft][2], acc[ot][ft][3]);
        *(uint2*)(Gt + ((size_t)(b * 4 + ot) * Fn + fg) * 8 + quad * 2) = pv;
      }
    }
  }
}

// K2: unchanged (best measured: 68 us). block = (b,seg) x 128 faces,
// 32 B rows, 2 lanes/row.
template<int WRITE_BF16>
__global__ __launch_bounds__(256) void k2_gather(
    const u32* __restrict__ Gt, const int* __restrict__ ring,
    const float* __restrict__ bias, u32* __restrict__ Y, float* __restrict__ outF,
    float* __restrict__ gsum, float* __restrict__ gsum2) {
  const int bid = blockIdx.x;
  const int combo = bid & 15;
  const int ft = bid >> 4;
  const int b = combo >> 2;
  const int seg = combo & 3;
  const int t = threadIdx.x;
  const int face_l = t >> 1;          // 0..127
  const int half = t & 1;
  const int fa = ft * 128 + face_l;
  const bool valid = fa < Fn;

  __shared__ float y_s[128][17];
  __shared__ float rs[16][17];
  __shared__ float rs2[16][17];

  float acc[8];
  #pragma unroll
  for (int i = 0; i < 8; i++) acc[i] = 0.f;

  const int c0 = seg * 16 + half * 8;
  float bv[8];
  #pragma unroll
  for (int i = 0; i < 8; i++) bv[i] = bias[c0 + i];

  if (valid) {
    const int4* rp = (const int4*)(ring + ((size_t)b * Fn + fa) * Kn);
    int4 i0 = rp[0], i1 = rp[1], i2 = rp[2], i3 = rp[3];
    int idx[16] = {i0.x,i0.y,i0.z,i0.w, i1.x,i1.y,i1.z,i1.w,
                   i2.x,i2.y,i2.z,i2.w, i3.x,i3.y,i3.z,i3.w};
    const uint4* Gs = (const uint4*)(Gt + (size_t)combo * Fn * 8);
    uint4 v[8], w[8];
    #pragma unroll
    for (int k = 0; k < 8; k++) v[k] = Gs[(size_t)idx[k] * 2 + half];
    #pragma unroll
    for (int k = 0; k < 8; k++) w[k] = Gs[(size_t)idx[8 + k] * 2 + half];
    #pragma unroll
    for (int k = 0; k < 8; k++) {
      u32 uu[4] = {v[k].x, v[k].y, v[k].z, v[k].w};
      #pragma unroll
      for (int p = 0; p < 4; p++) {
        acc[2*p]   += __uint_as_float(uu[p] << 16);
        acc[2*p+1] += __uint_as_float(uu[p] & 0xffff0000u);
      }
    }
    #pragma unroll
    for (int k = 0; k < 8; k++) {
      u32 uu[4] = {w[k].x, w[k].y, w[k].z, w[k].w};
      #pragma unroll
      for (int p = 0; p < 4; p++) {
        acc[2*p]   += __uint_as_float(uu[p] << 16);
        acc[2*p+1] += __uint_as_float(uu[p] & 0xffff0000u);
      }
    }
  }
  #pragma unroll
  for (int i = 0; i < 8; i++) acc[i] = valid ? acc[i] + bv[i] : 0.f;
  #pragma unroll
  for (int i = 0; i < 8; i++) y_s[face_l][half * 8 + i] = acc[i];
  __syncthreads();

  if (WRITE_BF16) {
    const int fp = t & 63, chb = t >> 6;   // 64 face-pairs x 4 ch-groups
    const int fa2 = ft * 64 + fp;
    if (fa2 * 2 < Fn) {
      #pragma unroll
      for (int j = 0; j < 4; j++) {
        int ch = chb * 4 + j;
        Y[((size_t)b * 64 + seg * 16 + ch) * (Fn / 2) + fa2] =
            pack2(y_s[fp * 2][ch], y_s[fp * 2 + 1][ch]);
      }
    }
  } else {
    const int fl2 = t & 127, chb = t >> 7;
    if (ft * 128 + fl2 < Fn) {
      float* ob = outF + ((size_t)b * 64 + seg * 16 + chb * 8) * Fn + ft * 128 + fl2;
      #pragma unroll
      for (int j = 0; j < 8; j++) ob[(size_t)j * Fn] = y_s[fl2][chb * 8 + j];
    }
  }

  {  // stats: 16 parts x 16 channels
    const int ch = t & 15, part = t >> 4;
    float s = 0.f, s2 = 0.f;
    #pragma unroll
    for (int i = 0; i < 8; i++) {
      float v = y_s[part * 8 + i][ch];
      s += v; s2 += v * v;
    }
    rs[part][ch] = s; rs2[part][ch] = s2;
  }
  __syncthreads();
  if (t < 16) {
    float s = 0.f;
    #pragma unroll
    for (int p = 0; p < 16; p++) s += rs[p][t];
    atomicAdd(&gsum[seg * 16 + t], s);
  } else if (t < 32) {
    const int ch = t - 16;
    float s2 = 0.f;
    #pragma unroll
    for (int p = 0; p < 16; p++) s2 += rs2[p][ch];
    atomicAdd(&gsum2[seg * 16 + ch], s2);
  }
}

__global__ void k3_stats(const float* __restrict__ gsum, const float* __restrict__ gsum2,
                         const float* __restrict__ gamma, const float* __restrict__ beta,
                         float* __restrict__ ab) {
  int o = threadIdx.x;
  if (o < 64) {
    float inv = 1.0f / (float)NTOT;
    float mean = gsum[o] * inv;
    float var = gsum2[o] * inv - mean * mean;  // biased
    float r = rsqrtf(var + EPS);
    float a = gamma[o] * r;
    ab[o] = a;
    ab[64 + o] = beta[o] - mean * a;
  }
}

// k4 (bf16, k3 fused): thread = one uint2 (4 faces) -> one float4 store.
// Reads 512 B / writes 1 KB contiguous per wave instr (fully coalesced).
__global__ __launch_bounds__(256) void k4_norm_bf(
    const u32* __restrict__ Y, const float* __restrict__ gsum,
    const float* __restrict__ gsum2, const float* __restrict__ gamma,
    const float* __restrict__ beta, float* __restrict__ out) {
  int i = blockIdx.x * 256 + threadIdx.x;   // uint2 index; 3.2M total, exact cover
  int ch = (i / 12500) & 63;                // Fn/4 = 12500 uint2 per channel row
  const float inv = 1.0f / (float)NTOT;
  float mean = gsum[ch] * inv;
  float var = gsum2[ch] * inv - mean * mean;
  float a = gamma[ch] * rsqrtf(var + EPS);
  float cc = beta[ch] - mean * a;
  uint2 u = ((const uint2*)Y)[i];
  float4 v;
  v.x = fmaxf(fmaf(__uint_as_float(u.x << 16), a, cc), 0.f);
  v.y = fmaxf(fmaf(__uint_as_float(u.x & 0xffff0000u), a, cc), 0.f);
  v.z = fmaxf(fmaf(__uint_as_float(u.y << 16), a, cc), 0.f);
  v.w = fmaxf(fmaf(__uint_as_float(u.y & 0xffff0000u), a, cc), 0.f);
  ((float4*)out)[i] = v;
}

// k4 (fallback): in-place fp32 normalize
__global__ __launch_bounds__(256) void k4_norm_f32(float* __restrict__ out,
                                                   const float* __restrict__ ab) {
  int i = blockIdx.x * 256 + threadIdx.x;   // float4 index
  int o = (i / (Fn / 4)) & 63;
  float a = ab[o], c = ab[64 + o];
  float4 v = ((float4*)out)[i];
  v.x = fmaxf(fmaf(v.x, a, c), 0.f);
  v.y = fmaxf(fmaf(v.y, a, c), 0.f);
  v.z = fmaxf(fmaf(v.z, a, c), 0.f);
  v.w = fmaxf(fmaf(v.w, a, c), 0.f);
  ((float4*)out)[i] = v;
}

extern "C" void kernel_launch(void* const* d_in, const int* in_sizes, int n_in,
                              void* d_out, int out_size, void* d_ws, size_t ws_size,
                              hipStream_t stream) {
  const float* fea   = (const float*)d_in[0];
  const int*   ring  = (const int*)d_in[1];
  const float* W     = (const float*)d_in[2];
  const float* bias  = (const float*)d_in[3];
  const float* gamma = (const float*)d_in[4];
  const float* beta  = (const float*)d_in[5];
  float* out = (float*)d_out;

  u32* Gt = (u32*)d_ws;                                   // [B*4][Fn][8 u32] = 25.6 MB
  const size_t gtBytes = (size_t)Bn * 4 * Fn * 8 * 4;
  const size_t yBytes  = (size_t)Bn * 64 * (Fn / 2) * 4;  // 25.6 MB
  const bool bf16y = ws_size >= gtBytes + yBytes + 1024;

  u32* Y = (u32*)((char*)d_ws + gtBytes);
  float* gsum  = bf16y ? (float*)((char*)d_ws + gtBytes + yBytes)
                       : (float*)((char*)d_ws + gtBytes);
  float* gsum2 = gsum + 64;
  float* ab    = gsum + 128;

  hipMemsetAsync(gsum, 0, 2 * 64 * sizeof(float), stream);
  k1_mfma<<<dim3((Fn + 127) / 128, Bn), 256, 0, stream>>>(fea, W, Gt);
  const int ftiles = (Fn + 127) / 128;                    // 391
  if (bf16y) {
    k2_gather<1><<<dim3(ftiles * 16), 256, 0, stream>>>(Gt, ring, bias, Y, out, gsum, gsum2);
    k4_norm_bf<<<dim3(Bn * 64 * 12500 / 256), 256, 0, stream>>>(Y, gsum, gsum2, gamma, beta, out);
  } else {
    k2_gather<0><<<dim3(ftiles * 16), 256, 0, stream>>>(Gt, ring, bias, Y, out, gsum, gsum2);
    k3_stats<<<1, 64, 0, stream>>>(gsum, gsum2, gamma, beta, ab);
    k4_norm_f32<<<dim3((Bn * Cn * Fn / 4) / 256), 256, 0, stream>>>(out, ab);
  }
}